// Round 1
// baseline (624.766 us; speedup 1.0000x reference)
//
#include <hip/hip_runtime.h>
#include <math.h>

constexpr int B_  = 16;
constexpr int C_  = 1536;
constexpr int T_  = 2000;
constexpr int H_  = 128;
constexpr int C3_ = 3 * C_;   // 4608
constexpr int C2_ = 2 * C_;   // 3072

// ---------------- K1: masked per-(b,c) mean/std over T (one wave per row) ----
__global__ __launch_bounds__(256) void k_stats(
    const float* __restrict__ x, const float* __restrict__ mask,
    float* __restrict__ mean0, float* __restrict__ std0) {
  const int wave = threadIdx.x >> 6;
  const int lane = threadIdx.x & 63;
  const int row = blockIdx.x * 4 + wave;      // b*C + c
  const int b = row / C_;
  const float4* xr = (const float4*)(x + (size_t)row * T_);
  const float4* mr = (const float4*)(mask + (size_t)b * T_);
  float sm = 0.f, s1 = 0.f, s2 = 0.f;
  for (int i = lane; i < T_ / 4; i += 64) {
    float4 xv = xr[i];
    float4 mv = mr[i];
    sm += mv.x + mv.y + mv.z + mv.w;
    s1 += mv.x * xv.x + mv.y * xv.y + mv.z * xv.z + mv.w * xv.w;
    s2 += mv.x * xv.x * xv.x + mv.y * xv.y * xv.y + mv.z * xv.z * xv.z + mv.w * xv.w * xv.w;
  }
#pragma unroll
  for (int off = 32; off; off >>= 1) {
    sm += __shfl_xor(sm, off);
    s1 += __shfl_xor(s1, off);
    s2 += __shfl_xor(s2, off);
  }
  if (lane == 0) {
    float mean = s1 / sm;
    float var = s2 / sm - mean * mean;
    mean0[row] = mean;
    std0[row] = sqrtf(fmaxf(var, 1e-5f));
  }
}

// ---------------- K2: hconst[b,h] = b1 + w1[:,C:2C]@mean0 + w1[:,2C:3C]@std0 --
__global__ __launch_bounds__(256) void k_hconst(
    const float* __restrict__ w1, const float* __restrict__ b1,
    const float* __restrict__ mean0, const float* __restrict__ std0,
    float* __restrict__ hconst) {
  const int wave = threadIdx.x >> 6;
  const int lane = threadIdx.x & 63;
  const int idx = blockIdx.x * 4 + wave;      // b*H + h
  const int b = idx >> 7;
  const int h = idx & (H_ - 1);
  const float* wm  = w1 + (size_t)h * C3_ + C_;
  const float* wsd = wm + C_;
  const float* mn = mean0 + b * C_;
  const float* sd = std0 + b * C_;
  float s = 0.f;
  for (int c = lane; c < C_; c += 64)
    s += wm[c] * mn[c] + wsd[c] * sd[c];
#pragma unroll
  for (int off = 32; off; off >>= 1) s += __shfl_xor(s, off);
  if (lane == 0) hconst[idx] = s + b1[h];
}

// ---------------- K3: h = tanh(LN_H(relu(w1c @ x + hconst))) ------------------
// block: 128h x 128t tile, 256 threads, 8x8 micro-tile. grid (16 t-tiles, B).
__global__ __launch_bounds__(256) void k_gemm1_ln(
    const float* __restrict__ x, const float* __restrict__ w1,
    const float* __restrict__ hconst, const float* __restrict__ g1,
    const float* __restrict__ be1, float* __restrict__ hln) {
  __shared__ __align__(16) float As[32][132];   // [k][h], padded
  __shared__ __align__(16) float Bs[32][128];   // [k][t]
  const int b = blockIdx.y;
  const int t0 = blockIdx.x * 128;
  const int tid = threadIdx.x;
  const int th = tid & 15;    // 8 h each
  const int tt = tid >> 4;    // 8 t each
  float acc[8][8];
#pragma unroll
  for (int i = 0; i < 8; ++i)
#pragma unroll
    for (int j = 0; j < 8; ++j) acc[i][j] = 0.f;

  for (int k0 = 0; k0 < C_; k0 += 32) {
    // stage w1[0:128][k0:k0+32] transposed: 1024 float4
#pragma unroll
    for (int it = 0; it < 4; ++it) {
      int j = tid + it * 256;
      int row = j >> 3, kk = (j & 7) << 2;
      float4 v = *(const float4*)(w1 + (size_t)row * C3_ + (k0 + kk));
      As[kk + 0][row] = v.x; As[kk + 1][row] = v.y;
      As[kk + 2][row] = v.z; As[kk + 3][row] = v.w;
    }
    // stage x[b][k0:k0+32][t0:t0+128]: 1024 float4 (zero-pad past T)
#pragma unroll
    for (int it = 0; it < 4; ++it) {
      int j = tid + it * 256;
      int kr = j >> 5, tq = (j & 31) << 2;
      int t = t0 + tq;
      float4 v = make_float4(0.f, 0.f, 0.f, 0.f);
      if (t + 3 < T_) v = *(const float4*)(x + (size_t)(b * C_ + k0 + kr) * T_ + t);
      *(float4*)&Bs[kr][tq] = v;
    }
    __syncthreads();
#pragma unroll
    for (int kk = 0; kk < 32; ++kk) {
      float4 a0 = *(const float4*)&As[kk][th * 8];
      float4 a1 = *(const float4*)&As[kk][th * 8 + 4];
      float4 b0 = *(const float4*)&Bs[kk][tt * 8];
      float4 b1v = *(const float4*)&Bs[kk][tt * 8 + 4];
      float a[8] = {a0.x, a0.y, a0.z, a0.w, a1.x, a1.y, a1.z, a1.w};
      float bb[8] = {b0.x, b0.y, b0.z, b0.w, b1v.x, b1v.y, b1v.z, b1v.w};
#pragma unroll
      for (int i = 0; i < 8; ++i)
#pragma unroll
        for (int j = 0; j < 8; ++j) acc[i][j] = fmaf(a[i], bb[j], acc[i][j]);
    }
    __syncthreads();
  }

  // epilogue: + hconst, relu, LN over 128 h per t-column, tanh, store
  float hc[8], g[8], be[8];
#pragma unroll
  for (int i = 0; i < 8; ++i) {
    int h = th * 8 + i;
    hc[i] = hconst[b * H_ + h];
    g[i]  = g1[h];
    be[i] = be1[h];
  }
  float sum[8], ssq[8];
#pragma unroll
  for (int j = 0; j < 8; ++j) { sum[j] = 0.f; ssq[j] = 0.f; }
#pragma unroll
  for (int i = 0; i < 8; ++i)
#pragma unroll
    for (int j = 0; j < 8; ++j) {
      float v = fmaxf(acc[i][j] + hc[i], 0.f);
      acc[i][j] = v;
      sum[j] += v;
      ssq[j] += v * v;
    }
  // 16 threads (th) share each t-column; they're contiguous lanes
#pragma unroll
  for (int off = 1; off < 16; off <<= 1) {
#pragma unroll
    for (int j = 0; j < 8; ++j) {
      sum[j] += __shfl_xor(sum[j], off);
      ssq[j] += __shfl_xor(ssq[j], off);
    }
  }
  float meanv[8], rstdv[8];
#pragma unroll
  for (int j = 0; j < 8; ++j) {
    float mean = sum[j] * (1.f / 128.f);
    meanv[j] = mean;
    rstdv[j] = rsqrtf(ssq[j] * (1.f / 128.f) - mean * mean + 1e-5f);
  }
  const int tb = t0 + tt * 8;
  if (tb < T_) {   // T_ % 8 == 0, so a t-group is fully valid or fully invalid
#pragma unroll
    for (int i = 0; i < 8; ++i) {
      float o[8];
#pragma unroll
      for (int j = 0; j < 8; ++j)
        o[j] = tanhf((acc[i][j] - meanv[j]) * rstdv[j] * g[i] + be[i]);
      float* dst = hln + (size_t)(b * H_ + th * 8 + i) * T_ + tb;
      *(float4*)dst = make_float4(o[0], o[1], o[2], o[3]);
      *(float4*)(dst + 4) = make_float4(o[4], o[5], o[6], o[7]);
    }
  }
}

// ---------------- K4: alpha = w2 @ hln, online masked softmax over T, ---------
//                  pooled = [sum(a*x), sqrt(max(sum(a*x^2)-mean^2, eps))]
// block: 96c x all-T for one b; t-chunks of 128; 256 threads, 6c x 8t micro.
constexpr int CT_ = 96;
__global__ __launch_bounds__(256) void k_gemm2_pool(
    const float* __restrict__ x, const float* __restrict__ mask,
    const float* __restrict__ w2, const float* __restrict__ hln,
    float* __restrict__ pooled) {
  __shared__ __align__(16) float Ws[H_][128];   // [h][slot] slot=tc*8+i (i<6)
  __shared__ __align__(16) float Bs[H_][128];   // [h][t]
  __shared__ __align__(16) float Ms[128];
  const int b = blockIdx.y;
  const int c0 = blockIdx.x * CT_;
  const int tid = threadIdx.x;
  const int tc = tid >> 4;   // 6 c each
  const int tt = tid & 15;   // 8 t each

  // stage w2 tile transposed into 8-wide slot groups (2 pad slots unused)
#pragma unroll
  for (int it = 0; it < 12; ++it) {
    int j = tid + it * 256;
    int row = j >> 5;
    int hh = (j & 31) << 2;
    float4 v = *(const float4*)(w2 + (size_t)(c0 + row) * H_ + hh);
    int slot = (row / 6) * 8 + (row % 6);
    Ws[hh + 0][slot] = v.x; Ws[hh + 1][slot] = v.y;
    Ws[hh + 2][slot] = v.z; Ws[hh + 3][slot] = v.w;
  }

  float m[6], s0[6], s1[6], s2[6];
#pragma unroll
  for (int i = 0; i < 6; ++i) { m[i] = -INFINITY; s0[i] = 0.f; s1[i] = 0.f; s2[i] = 0.f; }

  for (int t0 = 0; t0 < T_; t0 += 128) {
    __syncthreads();
#pragma unroll
    for (int it = 0; it < 16; ++it) {
      int j = tid + it * 256;
      int row = j >> 5;
      int tq = (j & 31) << 2;
      int t = t0 + tq;
      float4 v = make_float4(0.f, 0.f, 0.f, 0.f);
      if (t + 3 < T_) v = *(const float4*)(hln + (size_t)(b * H_ + row) * T_ + t);
      *(float4*)&Bs[row][tq] = v;
    }
    if (tid < 128) {
      int t = t0 + tid;
      Ms[tid] = (t < T_) ? mask[b * T_ + t] : 0.f;
    }
    __syncthreads();

    float acc[6][8];
#pragma unroll
    for (int i = 0; i < 6; ++i)
#pragma unroll
      for (int j = 0; j < 8; ++j) acc[i][j] = 0.f;

#pragma unroll 8
    for (int k = 0; k < H_; ++k) {
      float4 av = *(const float4*)&Ws[k][tc * 8];      // broadcast in 16-group
      float2 av2 = *(const float2*)&Ws[k][tc * 8 + 4];
      float4 bv0 = *(const float4*)&Bs[k][tt * 8];
      float4 bv1 = *(const float4*)&Bs[k][tt * 8 + 4];
      float a[6] = {av.x, av.y, av.z, av.w, av2.x, av2.y};
      float bb[8] = {bv0.x, bv0.y, bv0.z, bv0.w, bv1.x, bv1.y, bv1.z, bv1.w};
#pragma unroll
      for (int i = 0; i < 6; ++i)
#pragma unroll
        for (int j = 0; j < 8; ++j) acc[i][j] = fmaf(a[i], bb[j], acc[i][j]);
    }

    float mk[8];
    {
      float4 m0 = *(const float4*)&Ms[tt * 8];
      float4 m1 = *(const float4*)&Ms[tt * 8 + 4];
      mk[0]=m0.x; mk[1]=m0.y; mk[2]=m0.z; mk[3]=m0.w;
      mk[4]=m1.x; mk[5]=m1.y; mk[6]=m1.z; mk[7]=m1.w;
    }
    const int tbase = t0 + tt * 8;
#pragma unroll
    for (int i = 0; i < 6; ++i) {
      float lm = -INFINITY;
#pragma unroll
      for (int j = 0; j < 8; ++j)
        if (mk[j] != 0.f) lm = fmaxf(lm, acc[i][j]);
#pragma unroll
      for (int off = 1; off < 16; off <<= 1) lm = fmaxf(lm, __shfl_xor(lm, off));
      float mnew = fmaxf(m[i], lm);
      if (mnew == -INFINITY) continue;   // group-uniform: safe
      float xr[8];
      {
        const float* src = x + (size_t)(b * C_ + c0 + tc * 6 + i) * T_ + tbase;
        if (tbase + 7 < T_) {
          float4 x0 = *(const float4*)src;
          float4 x1 = *(const float4*)(src + 4);
          xr[0]=x0.x; xr[1]=x0.y; xr[2]=x0.z; xr[3]=x0.w;
          xr[4]=x1.x; xr[5]=x1.y; xr[6]=x1.z; xr[7]=x1.w;
        } else {
#pragma unroll
          for (int j = 0; j < 8; ++j) xr[j] = (tbase + j < T_) ? src[j] : 0.f;
        }
      }
      float scale = __expf(m[i] - mnew);   // m=-inf -> 0, no NaN (mnew finite)
      float p0 = 0.f, p1 = 0.f, p2 = 0.f;
#pragma unroll
      for (int j = 0; j < 8; ++j) {
        float e = (mk[j] != 0.f) ? __expf(acc[i][j] - mnew) : 0.f;
        p0 += e;
        p1 += e * xr[j];
        p2 += e * xr[j] * xr[j];
      }
#pragma unroll
      for (int off = 1; off < 16; off <<= 1) {
        p0 += __shfl_xor(p0, off);
        p1 += __shfl_xor(p1, off);
        p2 += __shfl_xor(p2, off);
      }
      s0[i] = s0[i] * scale + p0;
      s1[i] = s1[i] * scale + p1;
      s2[i] = s2[i] * scale + p2;
      m[i] = mnew;
    }
  }

  if (tt == 0) {
#pragma unroll
    for (int i = 0; i < 6; ++i) {
      int c = c0 + tc * 6 + i;
      float mean = s1[i] / s0[i];
      float var = s2[i] / s0[i] - mean * mean;
      pooled[b * C2_ + c] = mean;
      pooled[b * C2_ + C_ + c] = sqrtf(fmaxf(var, 1e-5f));
    }
  }
}

// ---------------- K5: final LN over 2C channels per b -------------------------
__global__ __launch_bounds__(256) void k_final_ln(
    const float* __restrict__ pooled, const float* __restrict__ g2,
    const float* __restrict__ be2, float* __restrict__ out) {
  __shared__ float rs[8];
  const int b = blockIdx.x;
  const int tid = threadIdx.x;
  const int lane = tid & 63;
  const int wave = tid >> 6;
  const float* p = pooled + b * C2_;
  float s = 0.f, q = 0.f;
  for (int i = tid; i < C2_; i += 256) {
    float v = p[i];
    s += v;
    q += v * v;
  }
#pragma unroll
  for (int off = 32; off; off >>= 1) {
    s += __shfl_xor(s, off);
    q += __shfl_xor(q, off);
  }
  if (lane == 0) { rs[wave] = s; rs[4 + wave] = q; }
  __syncthreads();
  s = rs[0] + rs[1] + rs[2] + rs[3];
  q = rs[4] + rs[5] + rs[6] + rs[7];
  float mean = s * (1.f / C2_);
  float var = q * (1.f / C2_) - mean * mean;
  float rstd = rsqrtf(var + 1e-5f);
  for (int i = tid; i < C2_; i += 256)
    out[b * C2_ + i] = (p[i] - mean) * rstd * g2[i] + be2[i];
}

extern "C" void kernel_launch(void* const* d_in, const int* in_sizes, int n_in,
                              void* d_out, int out_size, void* d_ws, size_t ws_size,
                              hipStream_t stream) {
  const float* x    = (const float*)d_in[0];
  const float* mask = (const float*)d_in[1];
  const float* w1   = (const float*)d_in[2];
  const float* b1   = (const float*)d_in[3];
  const float* g1   = (const float*)d_in[4];
  const float* be1  = (const float*)d_in[5];
  const float* w2   = (const float*)d_in[6];
  // d_in[7] = b2: per-(b,c) constant on softmax logits -> softmax-invariant, dropped
  const float* g2   = (const float*)d_in[8];
  const float* be2  = (const float*)d_in[9];
  float* out = (float*)d_out;

  float* ws     = (float*)d_ws;
  float* mean0  = ws;                  // B*C
  float* std0   = mean0 + B_ * C_;     // B*C
  float* hconst = std0 + B_ * C_;      // B*H
  float* pooled = hconst + B_ * H_;    // B*2C
  float* hln    = pooled + B_ * C2_;   // B*H*T (16.4 MB)

  k_stats<<<dim3(B_ * C_ / 4), dim3(256), 0, stream>>>(x, mask, mean0, std0);
  k_hconst<<<dim3(B_ * H_ / 4), dim3(256), 0, stream>>>(w1, b1, mean0, std0, hconst);
  k_gemm1_ln<<<dim3(16, B_), dim3(256), 0, stream>>>(x, w1, hconst, g1, be1, hln);
  k_gemm2_pool<<<dim3(16, B_), dim3(256), 0, stream>>>(x, mask, w2, hln, pooled);
  k_final_ln<<<dim3(B_), dim3(256), 0, stream>>>(pooled, g2, be2, out);
}

// Round 3
// 389.605 us; speedup vs baseline: 1.6036x; 1.6036x over previous
//
#include <hip/hip_runtime.h>
#include <math.h>

constexpr int B_  = 16;
constexpr int C_  = 1536;
constexpr int T_  = 2000;
constexpr int H_  = 128;
constexpr int C3_ = 3 * C_;   // 4608
constexpr int C2_ = 2 * C_;   // 3072

typedef short bf8 __attribute__((ext_vector_type(8)));   // 8 bf16 (4 VGPR) MFMA A/B frag
typedef short bf4 __attribute__((ext_vector_type(4)));   // 4 bf16 (8B)
typedef float f4  __attribute__((ext_vector_type(4)));   // MFMA C/D frag

// fp32 -> bf16 round-to-nearest-even (finite inputs only)
__device__ inline unsigned short f2b(float f) {
  unsigned int u = __builtin_bit_cast(unsigned int, f);
  unsigned int r = (u + 0x7FFFu + ((u >> 16) & 1u)) >> 16;
  return (unsigned short)r;
}

// ---------------- K1: masked per-(b,c) mean/std over T (one wave per row) ----
__global__ __launch_bounds__(256) void k_stats(
    const float* __restrict__ x, const float* __restrict__ mask,
    float* __restrict__ mean0, float* __restrict__ std0) {
  const int wave = threadIdx.x >> 6;
  const int lane = threadIdx.x & 63;
  const int row = blockIdx.x * 4 + wave;      // b*C + c
  const int b = row / C_;
  const float4* xr = (const float4*)(x + (size_t)row * T_);
  const float4* mr = (const float4*)(mask + (size_t)b * T_);
  float sm = 0.f, s1 = 0.f, s2 = 0.f;
  for (int i = lane; i < T_ / 4; i += 64) {
    float4 xv = xr[i];
    float4 mv = mr[i];
    sm += mv.x + mv.y + mv.z + mv.w;
    s1 += mv.x * xv.x + mv.y * xv.y + mv.z * xv.z + mv.w * xv.w;
    s2 += mv.x * xv.x * xv.x + mv.y * xv.y * xv.y + mv.z * xv.z * xv.z + mv.w * xv.w * xv.w;
  }
#pragma unroll
  for (int off = 32; off; off >>= 1) {
    sm += __shfl_xor(sm, off);
    s1 += __shfl_xor(s1, off);
    s2 += __shfl_xor(s2, off);
  }
  if (lane == 0) {
    float mean = s1 / sm;
    float var = s2 / sm - mean * mean;
    mean0[row] = mean;
    std0[row] = sqrtf(fmaxf(var, 1e-5f));
  }
}

// ---------------- K2: hconst[b,h] = b1 + w1[:,C:2C]@mean0 + w1[:,2C:3C]@std0 --
__global__ __launch_bounds__(256) void k_hconst(
    const float* __restrict__ w1, const float* __restrict__ b1,
    const float* __restrict__ mean0, const float* __restrict__ std0,
    float* __restrict__ hconst) {
  const int wave = threadIdx.x >> 6;
  const int lane = threadIdx.x & 63;
  const int idx = blockIdx.x * 4 + wave;      // b*H + h
  const int b = idx >> 7;
  const int h = idx & (H_ - 1);
  const float* wm  = w1 + (size_t)h * C3_ + C_;
  const float* wsd = wm + C_;
  const float* mn = mean0 + b * C_;
  const float* sd = std0 + b * C_;
  float s = 0.f;
  for (int c = lane; c < C_; c += 64)
    s += wm[c] * mn[c] + wsd[c] * sd[c];
#pragma unroll
  for (int off = 32; off; off >>= 1) s += __shfl_xor(s, off);
  if (lane == 0) hconst[idx] = s + b1[h];
}

// ---------------- K3: MFMA GEMM1 + relu + LN(H) + tanh -> hlnT[b][t][h] bf16 --
// block 256 thr (4 waves), tile 128h x 64t; wave w owns t-slice w*16..+15.
// LDS: A [128h][32k] bf16 rows 64B, B [64t][32k] bf16, XOR-swizzled, dbuf.
__global__ __launch_bounds__(256) void k_gemm1_ln(
    const float* __restrict__ x, const float* __restrict__ w1,
    const float* __restrict__ hconst, const float* __restrict__ g1,
    const float* __restrict__ be1, unsigned short* __restrict__ hlnT) {
  __shared__ __align__(16) short As[2][128 * 32];
  __shared__ __align__(16) short Bs[2][64 * 32];
  const int b = blockIdx.y;
  const int t0 = blockIdx.x * 64;
  const int tid = threadIdx.x;
  const int lane = tid & 63;
  const int w = tid >> 6;
  const int l15 = lane & 15;
  const int l4 = lane >> 4;

  float4 va[4], vb[2];

  f4 acc[8];
#pragma unroll
  for (int mi = 0; mi < 8; ++mi) { f4 z = {0.f, 0.f, 0.f, 0.f}; acc[mi] = z; }

  // ---- staging helpers (reg-staged: global fp32 -> regs -> bf16 LDS) ----
  // A: thread q-loop: idx=q*256+tid; row=idx>>3 (h), j4=idx&7 (float4 in k)
  // B: idx=q*256+tid; k=idx>>4, t4=idx&15 -> transpose into Bs[t][k]
#define G1_GLOAD(K0)                                                          \
  {                                                                           \
    _Pragma("unroll")                                                         \
    for (int q = 0; q < 4; ++q) {                                             \
      int idx = q * 256 + tid;                                                \
      int row = idx >> 3, j4 = idx & 7;                                       \
      va[q] = *(const float4*)(w1 + (size_t)row * C3_ + (K0) + j4 * 4);       \
    }                                                                         \
    _Pragma("unroll")                                                         \
    for (int q = 0; q < 2; ++q) {                                             \
      int idx = q * 256 + tid;                                                \
      int k = idx >> 4, t4 = idx & 15;                                        \
      int t = t0 + t4 * 4;                                                    \
      if (t < T_)                                                             \
        vb[q] = *(const float4*)(x + ((size_t)(b * C_ + (K0) + k)) * T_ + t); \
      else                                                                    \
        vb[q] = make_float4(0.f, 0.f, 0.f, 0.f);                              \
    }                                                                         \
  }
#define G1_LSTORE(BUF)                                                        \
  {                                                                           \
    _Pragma("unroll")                                                         \
    for (int q = 0; q < 4; ++q) {                                             \
      int idx = q * 256 + tid;                                                \
      int row = idx >> 3, j4 = idx & 7;                                       \
      int slot = (j4 >> 1) ^ ((row >> 2) & 3);                                \
      bf4 p;                                                                  \
      p[0] = (short)f2b(va[q].x); p[1] = (short)f2b(va[q].y);                 \
      p[2] = (short)f2b(va[q].z); p[3] = (short)f2b(va[q].w);                 \
      *(bf4*)&As[BUF][row * 32 + slot * 8 + (j4 & 1) * 4] = p;                \
    }                                                                         \
    _Pragma("unroll")                                                         \
    for (int q = 0; q < 2; ++q) {                                             \
      int idx = q * 256 + tid;                                                \
      int k = idx >> 4, t4 = idx & 15;                                        \
      float vv[4] = {vb[q].x, vb[q].y, vb[q].z, vb[q].w};                     \
      _Pragma("unroll")                                                       \
      for (int j = 0; j < 4; ++j) {                                           \
        int row = t4 * 4 + j;                                                 \
        int slot = (k >> 3) ^ ((row >> 2) & 3);                               \
        Bs[BUF][row * 32 + slot * 8 + (k & 7)] = (short)f2b(vv[j]);           \
      }                                                                       \
    }                                                                         \
  }

  G1_GLOAD(0);
  G1_LSTORE(0);
  __syncthreads();

  const int fA = (l15 >> 2) & 3;        // row-swizzle term, mi/w-independent
  const int NS = C_ / 32;               // 48 K-steps
  for (int s = 0; s < NS; ++s) {
    const int cur = s & 1;
    if (s + 1 < NS) G1_GLOAD((s + 1) * 32);
    {
      const int browB = w * 16 + l15;
      bf8 bfr = *(const bf8*)&Bs[cur][browB * 32 + (l4 ^ fA) * 8];
#pragma unroll
      for (int mi = 0; mi < 8; ++mi) {
        bf8 afr = *(const bf8*)&As[cur][(mi * 16 + l15) * 32 + (l4 ^ fA) * 8];
        acc[mi] = __builtin_amdgcn_mfma_f32_16x16x32_bf16(afr, bfr, acc[mi], 0, 0, 0);
      }
    }
    if (s + 1 < NS) G1_LSTORE(cur ^ 1);
    __syncthreads();
  }

  // epilogue: +hconst, relu, LN over 128 h (per t-col), tanh, bf16 store
  const int t = t0 + w * 16 + l15;
  float sum = 0.f, ssq = 0.f;
#pragma unroll
  for (int mi = 0; mi < 8; ++mi) {
    float4 h4 = *(const float4*)(hconst + b * H_ + mi * 16 + l4 * 4);
    const float* hp = (const float*)&h4;
#pragma unroll
    for (int reg = 0; reg < 4; ++reg) {
      float v = fmaxf(acc[mi][reg] + hp[reg], 0.f);
      acc[mi][reg] = v;
      sum += v;
      ssq += v * v;
    }
  }
  sum += __shfl_xor(sum, 16); sum += __shfl_xor(sum, 32);
  ssq += __shfl_xor(ssq, 16); ssq += __shfl_xor(ssq, 32);
  const float mean = sum * (1.f / 128.f);
  const float rstd = rsqrtf(ssq * (1.f / 128.f) - mean * mean + 1e-5f);
  if (t < T_) {
    unsigned short* dst = hlnT + ((size_t)b * T_ + t) * H_;
#pragma unroll
    for (int mi = 0; mi < 8; ++mi) {
      float4 g4 = *(const float4*)(g1 + mi * 16 + l4 * 4);
      float4 e4 = *(const float4*)(be1 + mi * 16 + l4 * 4);
      const float* gp = (const float*)&g4;
      const float* ep = (const float*)&e4;
      bf4 p;
#pragma unroll
      for (int reg = 0; reg < 4; ++reg) {
        float o = tanhf((acc[mi][reg] - mean) * rstd * gp[reg] + ep[reg]);
        p[reg] = (short)f2b(o);
      }
      *(bf4*)&dst[mi * 16 + l4 * 4] = p;
    }
  }
}

// ---------------- K4: MFMA GEMM2 (alpha=w2@hln) + flash softmax + pooling ----
// block 256 thr, c-tile 128, loop t-chunks of 64. wave w owns c rows w*32..+31.
// Per-LANE online softmax state (no cross-lane work in loop); merge at end.
__global__ __launch_bounds__(256) void k_gemm2_pool(
    const float* __restrict__ x, const float* __restrict__ mask,
    const float* __restrict__ w2, const unsigned short* __restrict__ hlnT,
    float* __restrict__ pooled) {
  __shared__ __align__(16) short Ws[128 * 128];     // [c][h] swizzled, 32KB
  __shared__ __align__(16) short Hs[2][64 * 128];   // [t][h] swizzled, 2x16KB
  const int b = blockIdx.y;
  const int c0 = blockIdx.x * 128;
  const int tid = threadIdx.x;
  const int lane = tid & 63;
  const int w = tid >> 6;
  const int l15 = lane & 15;
  const int l4 = lane >> 4;

  // stage w2 tile (fp32, L2-resident) -> Ws bf16 once: 128 rows x 128 h
  // (R2 BUG was here: only staged half the tile. Now q<16, row=idx>>5, j4=idx&31.)
#pragma unroll
  for (int q = 0; q < 16; ++q) {
    int idx = q * 256 + tid;
    int row = idx >> 5, j4 = idx & 31;
    float4 v = *(const float4*)(w2 + (size_t)(c0 + row) * H_ + j4 * 4);
    bf4 p;
    p[0] = (short)f2b(v.x); p[1] = (short)f2b(v.y);
    p[2] = (short)f2b(v.z); p[3] = (short)f2b(v.w);
    int slot = (j4 >> 1) ^ (row & 15);
    *(bf4*)&Ws[row * 128 + slot * 8 + (j4 & 1) * 4] = p;
  }

  float mmax[8], s0[8], s1[8], s2[8];
#pragma unroll
  for (int r = 0; r < 8; ++r) { mmax[r] = -INFINITY; s0[r] = 0.f; s1[r] = 0.f; s2[r] = 0.f; }

  bf8 hreg[4];
#define G2_HLOAD(T0)                                                          \
  {                                                                           \
    _Pragma("unroll")                                                         \
    for (int q = 0; q < 4; ++q) {                                             \
      int idx = q * 256 + tid;                                                \
      int row = idx >> 4, slot = idx & 15;                                    \
      int t = (T0) + row;                                                     \
      if (t > T_ - 1) t = T_ - 1;                                             \
      hreg[q] = *(const bf8*)(hlnT + ((size_t)b * T_ + t) * H_ + slot * 8);   \
    }                                                                         \
  }
#define G2_HSTORE(BUF)                                                        \
  {                                                                           \
    _Pragma("unroll")                                                         \
    for (int q = 0; q < 4; ++q) {                                             \
      int idx = q * 256 + tid;                                                \
      int row = idx >> 4, slot = idx & 15;                                    \
      *(bf8*)&Hs[BUF][row * 128 + (slot ^ (row & 15)) * 8] = hreg[q];         \
    }                                                                         \
  }

  G2_HLOAD(0);
  G2_HSTORE(0);
  __syncthreads();

  const int NCH = (T_ + 63) / 64;   // 32
  for (int ch = 0; ch < NCH; ++ch) {
    const int t0 = ch * 64;
    const int cur = ch & 1;
    if (ch + 1 < NCH) G2_HLOAD(t0 + 64);

    f4 acc[2][4];
#pragma unroll
    for (int mi = 0; mi < 2; ++mi)
#pragma unroll
      for (int nj = 0; nj < 4; ++nj) { f4 z = {0.f, 0.f, 0.f, 0.f}; acc[mi][nj] = z; }

#pragma unroll
    for (int ks = 0; ks < 4; ++ks) {
      const int sw = (ks * 4 + l4) ^ l15;   // row&15 == l15 for both A rows
      bf8 a0 = *(const bf8*)&Ws[(w * 32 + l15) * 128 + sw * 8];
      bf8 a1 = *(const bf8*)&Ws[(w * 32 + 16 + l15) * 128 + sw * 8];
      bf8 bb[4];
#pragma unroll
      for (int nj = 0; nj < 4; ++nj)
        bb[nj] = *(const bf8*)&Hs[cur][(nj * 16 + l15) * 128 + sw * 8];
#pragma unroll
      for (int nj = 0; nj < 4; ++nj) {
        acc[0][nj] = __builtin_amdgcn_mfma_f32_16x16x32_bf16(a0, bb[nj], acc[0][nj], 0, 0, 0);
        acc[1][nj] = __builtin_amdgcn_mfma_f32_16x16x32_bf16(a1, bb[nj], acc[1][nj], 0, 0, 0);
      }
    }

    // epilogue: per-lane online softmax + pooled partial sums
    float mk[4];
    int tcol[4];
#pragma unroll
    for (int nj = 0; nj < 4; ++nj) {
      int t = t0 + nj * 16 + l15;
      tcol[nj] = (t < T_) ? t : (T_ - 1);
      mk[nj] = (t < T_) ? mask[(size_t)b * T_ + t] : 0.f;
    }
#pragma unroll
    for (int mi = 0; mi < 2; ++mi)
#pragma unroll
      for (int reg = 0; reg < 4; ++reg) {
        const int r = mi * 4 + reg;
        const int c = c0 + w * 32 + mi * 16 + l4 * 4 + reg;
        float lm = mmax[r];
#pragma unroll
        for (int nj = 0; nj < 4; ++nj)
          if (mk[nj] != 0.f) lm = fmaxf(lm, acc[mi][nj][reg]);
        if (lm == -INFINITY) continue;
        const float scale = (mmax[r] == -INFINITY) ? 0.f : __expf(mmax[r] - lm);
        float a0 = s0[r] * scale, a1 = s1[r] * scale, a2 = s2[r] * scale;
#pragma unroll
        for (int nj = 0; nj < 4; ++nj) {
          if (mk[nj] != 0.f) {
            float e = __expf(acc[mi][nj][reg] - lm);
            float xv = x[((size_t)(b * C_ + c)) * T_ + tcol[nj]];
            a0 += e; a1 += e * xv; a2 += e * xv * xv;
          }
        }
        s0[r] = a0; s1[r] = a1; s2[r] = a2; mmax[r] = lm;
      }

    if (ch + 1 < NCH) G2_HSTORE(cur ^ 1);
    __syncthreads();
  }

  // merge the 16 lanes (cols) of each row group via log-sum-exp butterfly
#pragma unroll
  for (int off = 1; off < 16; off <<= 1) {
#pragma unroll
    for (int r = 0; r < 8; ++r) {
      float om = __shfl_xor(mmax[r], off);
      float o0 = __shfl_xor(s0[r], off);
      float o1 = __shfl_xor(s1[r], off);
      float o2 = __shfl_xor(s2[r], off);
      float mn = fmaxf(mmax[r], om);
      float e1 = (mmax[r] == -INFINITY) ? 0.f : __expf(mmax[r] - mn);
      float e2 = (om == -INFINITY) ? 0.f : __expf(om - mn);
      s0[r] = s0[r] * e1 + o0 * e2;
      s1[r] = s1[r] * e1 + o1 * e2;
      s2[r] = s2[r] * e1 + o2 * e2;
      mmax[r] = mn;
    }
  }
  if (l15 == 0) {
#pragma unroll
    for (int mi = 0; mi < 2; ++mi)
#pragma unroll
      for (int reg = 0; reg < 4; ++reg) {
        const int r = mi * 4 + reg;
        const int c = c0 + w * 32 + mi * 16 + l4 * 4 + reg;
        float mean = s1[r] / s0[r];
        float var = s2[r] / s0[r] - mean * mean;
        pooled[b * C2_ + c] = mean;
        pooled[b * C2_ + C_ + c] = sqrtf(fmaxf(var, 1e-5f));
      }
  }
}

// ---------------- K5: final LN over 2C channels per b -------------------------
__global__ __launch_bounds__(256) void k_final_ln(
    const float* __restrict__ pooled, const float* __restrict__ g2,
    const float* __restrict__ be2, float* __restrict__ out) {
  __shared__ float rs[8];
  const int b = blockIdx.x;
  const int tid = threadIdx.x;
  const int lane = tid & 63;
  const int wave = tid >> 6;
  const float* p = pooled + b * C2_;
  float s = 0.f, q = 0.f;
  for (int i = tid; i < C2_; i += 256) {
    float v = p[i];
    s += v;
    q += v * v;
  }
#pragma unroll
  for (int off = 32; off; off >>= 1) {
    s += __shfl_xor(s, off);
    q += __shfl_xor(q, off);
  }
  if (lane == 0) { rs[wave] = s; rs[4 + wave] = q; }
  __syncthreads();
  s = rs[0] + rs[1] + rs[2] + rs[3];
  q = rs[4] + rs[5] + rs[6] + rs[7];
  float mean = s * (1.f / C2_);
  float var = q * (1.f / C2_) - mean * mean;
  float rstd = rsqrtf(var + 1e-5f);
  for (int i = tid; i < C2_; i += 256)
    out[b * C2_ + i] = (p[i] - mean) * rstd * g2[i] + be2[i];
}

extern "C" void kernel_launch(void* const* d_in, const int* in_sizes, int n_in,
                              void* d_out, int out_size, void* d_ws, size_t ws_size,
                              hipStream_t stream) {
  const float* x    = (const float*)d_in[0];
  const float* mask = (const float*)d_in[1];
  const float* w1   = (const float*)d_in[2];
  const float* b1   = (const float*)d_in[3];
  const float* g1   = (const float*)d_in[4];
  const float* be1  = (const float*)d_in[5];
  const float* w2   = (const float*)d_in[6];
  // d_in[7] = b2: per-(b,c) constant on softmax logits -> softmax-invariant, dropped
  const float* g2   = (const float*)d_in[8];
  const float* be2  = (const float*)d_in[9];
  float* out = (float*)d_out;

  float* ws     = (float*)d_ws;
  float* mean0  = ws;                   // B*C
  float* std0   = mean0 + B_ * C_;      // B*C
  float* hconst = std0 + B_ * C_;       // B*H
  float* pooled = hconst + B_ * H_;     // B*2C
  unsigned short* hlnT = (unsigned short*)(pooled + B_ * C2_);  // B*T*H bf16, 8.2MB

  k_stats<<<dim3(B_ * C_ / 4), dim3(256), 0, stream>>>(x, mask, mean0, std0);
  k_hconst<<<dim3(B_ * H_ / 4), dim3(256), 0, stream>>>(w1, b1, mean0, std0, hconst);
  k_gemm1_ln<<<dim3((T_ + 63) / 64, B_), dim3(256), 0, stream>>>(x, w1, hconst, g1, be1, hlnT);
  k_gemm2_pool<<<dim3(C_ / 128, B_), dim3(256), 0, stream>>>(x, mask, w2, hlnT, pooled);
  k_final_ln<<<dim3(B_), dim3(256), 0, stream>>>(pooled, g2, be2, out);
}

// Round 4
// 183.559 us; speedup vs baseline: 3.4036x; 2.1225x over previous
//
#include <hip/hip_runtime.h>
#include <math.h>

constexpr int B_  = 16;
constexpr int C_  = 1536;
constexpr int T_  = 2000;
constexpr int H_  = 128;
constexpr int C3_ = 3 * C_;   // 4608
constexpr int C2_ = 2 * C_;   // 3072
constexpr int NT_ = 4;        // t-parts for gemm2 (512 t each)

typedef short bf8 __attribute__((ext_vector_type(8)));   // 8 bf16 (4 VGPR) MFMA A/B frag
typedef short bf4 __attribute__((ext_vector_type(4)));   // 4 bf16 (8B)
typedef float f4  __attribute__((ext_vector_type(4)));   // MFMA C/D frag

// fp32 -> bf16 round-to-nearest-even (finite inputs only)
__device__ inline unsigned short f2b(float f) {
  unsigned int u = __builtin_bit_cast(unsigned int, f);
  unsigned int r = (u + 0x7FFFu + ((u >> 16) & 1u)) >> 16;
  return (unsigned short)r;
}

// ---------------- K1: masked per-(b,c) mean/std over T (one wave per row) ----
__global__ __launch_bounds__(256) void k_stats(
    const float* __restrict__ x, const float* __restrict__ mask,
    float* __restrict__ mean0, float* __restrict__ std0) {
  const int wave = threadIdx.x >> 6;
  const int lane = threadIdx.x & 63;
  const int row = blockIdx.x * 4 + wave;      // b*C + c
  const int b = row / C_;
  const float4* xr = (const float4*)(x + (size_t)row * T_);
  const float4* mr = (const float4*)(mask + (size_t)b * T_);
  float sm = 0.f, s1 = 0.f, s2 = 0.f;
  for (int i = lane; i < T_ / 4; i += 64) {
    float4 xv = xr[i];
    float4 mv = mr[i];
    sm += mv.x + mv.y + mv.z + mv.w;
    s1 += mv.x * xv.x + mv.y * xv.y + mv.z * xv.z + mv.w * xv.w;
    s2 += mv.x * xv.x * xv.x + mv.y * xv.y * xv.y + mv.z * xv.z * xv.z + mv.w * xv.w * xv.w;
  }
#pragma unroll
  for (int off = 32; off; off >>= 1) {
    sm += __shfl_xor(sm, off);
    s1 += __shfl_xor(s1, off);
    s2 += __shfl_xor(s2, off);
  }
  if (lane == 0) {
    float mean = s1 / sm;
    float var = s2 / sm - mean * mean;
    mean0[row] = mean;
    std0[row] = sqrtf(fmaxf(var, 1e-5f));
  }
}

// ---------------- K2: hconst[b,h] = b1 + w1[:,C:2C]@mean0 + w1[:,2C:3C]@std0 --
__global__ __launch_bounds__(256) void k_hconst(
    const float* __restrict__ w1, const float* __restrict__ b1,
    const float* __restrict__ mean0, const float* __restrict__ std0,
    float* __restrict__ hconst) {
  const int wave = threadIdx.x >> 6;
  const int lane = threadIdx.x & 63;
  const int idx = blockIdx.x * 4 + wave;      // b*H + h
  const int b = idx >> 7;
  const int h = idx & (H_ - 1);
  const float* wm  = w1 + (size_t)h * C3_ + C_;
  const float* wsd = wm + C_;
  const float* mn = mean0 + b * C_;
  const float* sd = std0 + b * C_;
  float s = 0.f;
  for (int c = lane; c < C_; c += 64)
    s += wm[c] * mn[c] + wsd[c] * sd[c];
#pragma unroll
  for (int off = 32; off; off >>= 1) s += __shfl_xor(s, off);
  if (lane == 0) hconst[idx] = s + b1[h];
}

// ---------------- K3: MFMA GEMM1 + relu + LN(H) + tanh -> hlnT[b][t][h] bf16 --
// block 256 thr (4 waves), tile 128h x 64t; wave w owns t-slice w*16..+15.
// LDS: A [128h][32k] bf16 rows 64B, B [64t][32k] bf16, XOR-swizzled, dbuf.
__global__ __launch_bounds__(256) void k_gemm1_ln(
    const float* __restrict__ x, const float* __restrict__ w1,
    const float* __restrict__ hconst, const float* __restrict__ g1,
    const float* __restrict__ be1, unsigned short* __restrict__ hlnT) {
  __shared__ __align__(16) short As[2][128 * 32];
  __shared__ __align__(16) short Bs[2][64 * 32];
  const int b = blockIdx.y;
  const int t0 = blockIdx.x * 64;
  const int tid = threadIdx.x;
  const int lane = tid & 63;
  const int w = tid >> 6;
  const int l15 = lane & 15;
  const int l4 = lane >> 4;

  float4 va[4], vb[2];

  f4 acc[8];
#pragma unroll
  for (int mi = 0; mi < 8; ++mi) { f4 z = {0.f, 0.f, 0.f, 0.f}; acc[mi] = z; }

  // ---- staging helpers (reg-staged: global fp32 -> regs -> bf16 LDS) ----
#define G1_GLOAD(K0)                                                          \
  {                                                                           \
    _Pragma("unroll")                                                         \
    for (int q = 0; q < 4; ++q) {                                             \
      int idx = q * 256 + tid;                                                \
      int row = idx >> 3, j4 = idx & 7;                                       \
      va[q] = *(const float4*)(w1 + (size_t)row * C3_ + (K0) + j4 * 4);       \
    }                                                                         \
    _Pragma("unroll")                                                         \
    for (int q = 0; q < 2; ++q) {                                             \
      int idx = q * 256 + tid;                                                \
      int k = idx >> 4, t4 = idx & 15;                                        \
      int t = t0 + t4 * 4;                                                    \
      if (t < T_)                                                             \
        vb[q] = *(const float4*)(x + ((size_t)(b * C_ + (K0) + k)) * T_ + t); \
      else                                                                    \
        vb[q] = make_float4(0.f, 0.f, 0.f, 0.f);                              \
    }                                                                         \
  }
#define G1_LSTORE(BUF)                                                        \
  {                                                                           \
    _Pragma("unroll")                                                         \
    for (int q = 0; q < 4; ++q) {                                             \
      int idx = q * 256 + tid;                                                \
      int row = idx >> 3, j4 = idx & 7;                                       \
      int slot = (j4 >> 1) ^ ((row >> 2) & 3);                                \
      bf4 p;                                                                  \
      p[0] = (short)f2b(va[q].x); p[1] = (short)f2b(va[q].y);                 \
      p[2] = (short)f2b(va[q].z); p[3] = (short)f2b(va[q].w);                 \
      *(bf4*)&As[BUF][row * 32 + slot * 8 + (j4 & 1) * 4] = p;                \
    }                                                                         \
    _Pragma("unroll")                                                         \
    for (int q = 0; q < 2; ++q) {                                             \
      int idx = q * 256 + tid;                                                \
      int k = idx >> 4, t4 = idx & 15;                                        \
      float vv[4] = {vb[q].x, vb[q].y, vb[q].z, vb[q].w};                     \
      _Pragma("unroll")                                                       \
      for (int j = 0; j < 4; ++j) {                                           \
        int row = t4 * 4 + j;                                                 \
        int slot = (k >> 3) ^ ((row >> 2) & 3);                               \
        Bs[BUF][row * 32 + slot * 8 + (k & 7)] = (short)f2b(vv[j]);           \
      }                                                                       \
    }                                                                         \
  }

  G1_GLOAD(0);
  G1_LSTORE(0);
  __syncthreads();

  const int fA = (l15 >> 2) & 3;        // row-swizzle term, mi/w-independent
  const int NS = C_ / 32;               // 48 K-steps
  for (int s = 0; s < NS; ++s) {
    const int cur = s & 1;
    if (s + 1 < NS) G1_GLOAD((s + 1) * 32);
    {
      const int browB = w * 16 + l15;
      bf8 bfr = *(const bf8*)&Bs[cur][browB * 32 + (l4 ^ fA) * 8];
#pragma unroll
      for (int mi = 0; mi < 8; ++mi) {
        bf8 afr = *(const bf8*)&As[cur][(mi * 16 + l15) * 32 + (l4 ^ fA) * 8];
        acc[mi] = __builtin_amdgcn_mfma_f32_16x16x32_bf16(afr, bfr, acc[mi], 0, 0, 0);
      }
    }
    if (s + 1 < NS) G1_LSTORE(cur ^ 1);
    __syncthreads();
  }

  // epilogue: +hconst, relu, LN over 128 h (per t-col), tanh, bf16 store
  const int t = t0 + w * 16 + l15;
  float sum = 0.f, ssq = 0.f;
#pragma unroll
  for (int mi = 0; mi < 8; ++mi) {
    float4 h4 = *(const float4*)(hconst + b * H_ + mi * 16 + l4 * 4);
    const float* hp = (const float*)&h4;
#pragma unroll
    for (int reg = 0; reg < 4; ++reg) {
      float v = fmaxf(acc[mi][reg] + hp[reg], 0.f);
      acc[mi][reg] = v;
      sum += v;
      ssq += v * v;
    }
  }
  sum += __shfl_xor(sum, 16); sum += __shfl_xor(sum, 32);
  ssq += __shfl_xor(ssq, 16); ssq += __shfl_xor(ssq, 32);
  const float mean = sum * (1.f / 128.f);
  const float rstd = rsqrtf(ssq * (1.f / 128.f) - mean * mean + 1e-5f);
  if (t < T_) {
    unsigned short* dst = hlnT + ((size_t)b * T_ + t) * H_;
#pragma unroll
    for (int mi = 0; mi < 8; ++mi) {
      float4 g4 = *(const float4*)(g1 + mi * 16 + l4 * 4);
      float4 e4 = *(const float4*)(be1 + mi * 16 + l4 * 4);
      const float* gp = (const float*)&g4;
      const float* ep = (const float*)&e4;
      bf4 p;
#pragma unroll
      for (int reg = 0; reg < 4; ++reg) {
        float o = tanhf((acc[mi][reg] - mean) * rstd * gp[reg] + ep[reg]);
        p[reg] = (short)f2b(o);
      }
      *(bf4*)&dst[mi * 16 + l4 * 4] = p;
    }
  }
}

// ---------------- K4: MFMA GEMM2 (alpha=w2@hln) + flash softmax + pooling ----
// grid (12 c-tiles, B, NT parts). Each part owns t in [part*512, min(+512,T)).
// Per-LANE online softmax state; lane-merge at end; per-part partials to ws;
// k_pool_merge LSE-merges the NT parts.
__global__ __launch_bounds__(256) void k_gemm2_pool(
    const float* __restrict__ x, const float* __restrict__ mask,
    const float* __restrict__ w2, const unsigned short* __restrict__ hlnT,
    float* __restrict__ pm, float* __restrict__ ps0,
    float* __restrict__ ps1, float* __restrict__ ps2) {
  __shared__ __align__(16) short Ws[128 * 128];     // [c][h] swizzled, 32KB
  __shared__ __align__(16) short Hs[2][64 * 128];   // [t][h] swizzled, 2x16KB
  const int b = blockIdx.y;
  const int c0 = blockIdx.x * 128;
  const int part = blockIdx.z;
  const int tb = part * 512;
  const int te = min(tb + 512, T_);
  const int tid = threadIdx.x;
  const int lane = tid & 63;
  const int w = tid >> 6;
  const int l15 = lane & 15;
  const int l4 = lane >> 4;

  // stage w2 tile (fp32, L2-resident) -> Ws bf16 once: 128 rows x 128 h
#pragma unroll
  for (int q = 0; q < 16; ++q) {
    int idx = q * 256 + tid;
    int row = idx >> 5, j4 = idx & 31;
    float4 v = *(const float4*)(w2 + (size_t)(c0 + row) * H_ + j4 * 4);
    bf4 p;
    p[0] = (short)f2b(v.x); p[1] = (short)f2b(v.y);
    p[2] = (short)f2b(v.z); p[3] = (short)f2b(v.w);
    int slot = (j4 >> 1) ^ (row & 15);
    *(bf4*)&Ws[row * 128 + slot * 8 + (j4 & 1) * 4] = p;
  }

  float mmax[8], s0[8], s1[8], s2[8];
#pragma unroll
  for (int r = 0; r < 8; ++r) { mmax[r] = -INFINITY; s0[r] = 0.f; s1[r] = 0.f; s2[r] = 0.f; }

  bf8 hreg[4];
#define G2_HLOAD(T0)                                                          \
  {                                                                           \
    _Pragma("unroll")                                                         \
    for (int q = 0; q < 4; ++q) {                                             \
      int idx = q * 256 + tid;                                                \
      int row = idx >> 4, slot = idx & 15;                                    \
      int t = (T0) + row;                                                     \
      if (t > T_ - 1) t = T_ - 1;                                             \
      hreg[q] = *(const bf8*)(hlnT + ((size_t)b * T_ + t) * H_ + slot * 8);   \
    }                                                                         \
  }
#define G2_HSTORE(BUF)                                                        \
  {                                                                           \
    _Pragma("unroll")                                                         \
    for (int q = 0; q < 4; ++q) {                                             \
      int idx = q * 256 + tid;                                                \
      int row = idx >> 4, slot = idx & 15;                                    \
      *(bf8*)&Hs[BUF][row * 128 + (slot ^ (row & 15)) * 8] = hreg[q];         \
    }                                                                         \
  }

  G2_HLOAD(tb);
  G2_HSTORE(0);
  __syncthreads();

  const int NCH = (te - tb + 63) / 64;   // <= 8
  for (int ch = 0; ch < NCH; ++ch) {
    const int t0 = tb + ch * 64;
    const int cur = ch & 1;
    if (ch + 1 < NCH) G2_HLOAD(t0 + 64);

    // T14 issue-early: mask + x loads for this chunk, consumed after MFMA
    float mk[4];
    int tcol[4];
#pragma unroll
    for (int nj = 0; nj < 4; ++nj) {
      int t = t0 + nj * 16 + l15;
      tcol[nj] = (t < T_) ? t : (T_ - 1);
      mk[nj] = (t < T_) ? mask[(size_t)b * T_ + t] : 0.f;
    }
    float xv[8][4];
#pragma unroll
    for (int mi = 0; mi < 2; ++mi)
#pragma unroll
      for (int reg = 0; reg < 4; ++reg) {
        const int c = c0 + w * 32 + mi * 16 + l4 * 4 + reg;
        const float* xrow = x + ((size_t)(b * C_ + c)) * T_;
#pragma unroll
        for (int nj = 0; nj < 4; ++nj) xv[mi * 4 + reg][nj] = xrow[tcol[nj]];
      }

    f4 acc[2][4];
#pragma unroll
    for (int mi = 0; mi < 2; ++mi)
#pragma unroll
      for (int nj = 0; nj < 4; ++nj) { f4 z = {0.f, 0.f, 0.f, 0.f}; acc[mi][nj] = z; }

#pragma unroll
    for (int ks = 0; ks < 4; ++ks) {
      const int sw = (ks * 4 + l4) ^ l15;   // row&15 == l15 for both A rows
      bf8 a0 = *(const bf8*)&Ws[(w * 32 + l15) * 128 + sw * 8];
      bf8 a1 = *(const bf8*)&Ws[(w * 32 + 16 + l15) * 128 + sw * 8];
      bf8 bb[4];
#pragma unroll
      for (int nj = 0; nj < 4; ++nj)
        bb[nj] = *(const bf8*)&Hs[cur][(nj * 16 + l15) * 128 + sw * 8];
#pragma unroll
      for (int nj = 0; nj < 4; ++nj) {
        acc[0][nj] = __builtin_amdgcn_mfma_f32_16x16x32_bf16(a0, bb[nj], acc[0][nj], 0, 0, 0);
        acc[1][nj] = __builtin_amdgcn_mfma_f32_16x16x32_bf16(a1, bb[nj], acc[1][nj], 0, 0, 0);
      }
    }

    // epilogue: per-lane online softmax + pooled partial sums
#pragma unroll
    for (int mi = 0; mi < 2; ++mi)
#pragma unroll
      for (int reg = 0; reg < 4; ++reg) {
        const int r = mi * 4 + reg;
        float lm = mmax[r];
#pragma unroll
        for (int nj = 0; nj < 4; ++nj)
          if (mk[nj] != 0.f) lm = fmaxf(lm, acc[mi][nj][reg]);
        if (lm == -INFINITY) continue;
        const float scale = (mmax[r] == -INFINITY) ? 0.f : __expf(mmax[r] - lm);
        float a0 = s0[r] * scale, a1 = s1[r] * scale, a2 = s2[r] * scale;
#pragma unroll
        for (int nj = 0; nj < 4; ++nj) {
          if (mk[nj] != 0.f) {
            float e = __expf(acc[mi][nj][reg] - lm);
            float xvv = xv[r][nj];
            a0 += e; a1 += e * xvv; a2 += e * xvv * xvv;
          }
        }
        s0[r] = a0; s1[r] = a1; s2[r] = a2; mmax[r] = lm;
      }

    if (ch + 1 < NCH) G2_HSTORE(cur ^ 1);
    __syncthreads();
  }

  // merge the 16 lanes (cols) of each row group via log-sum-exp butterfly
#pragma unroll
  for (int off = 1; off < 16; off <<= 1) {
#pragma unroll
    for (int r = 0; r < 8; ++r) {
      float om = __shfl_xor(mmax[r], off);
      float o0 = __shfl_xor(s0[r], off);
      float o1 = __shfl_xor(s1[r], off);
      float o2 = __shfl_xor(s2[r], off);
      float mn = fmaxf(mmax[r], om);
      float e1 = (mmax[r] == -INFINITY) ? 0.f : __expf(mmax[r] - mn);
      float e2 = (om == -INFINITY) ? 0.f : __expf(om - mn);
      s0[r] = s0[r] * e1 + o0 * e2;
      s1[r] = s1[r] * e1 + o1 * e2;
      s2[r] = s2[r] * e1 + o2 * e2;
      mmax[r] = mn;
    }
  }
  if (l15 == 0) {
#pragma unroll
    for (int mi = 0; mi < 2; ++mi)
#pragma unroll
      for (int reg = 0; reg < 4; ++reg) {
        const int r = mi * 4 + reg;
        const int c = c0 + w * 32 + mi * 16 + l4 * 4 + reg;
        const size_t j = ((size_t)(b * NT_ + part)) * C_ + c;
        pm[j] = mmax[r]; ps0[j] = s0[r]; ps1[j] = s1[r]; ps2[j] = s2[r];
      }
  }
}

// ---------------- K4b: LSE-merge the NT t-part partials -> pooled ------------
__global__ __launch_bounds__(256) void k_pool_merge(
    const float* __restrict__ pm, const float* __restrict__ ps0,
    const float* __restrict__ ps1, const float* __restrict__ ps2,
    float* __restrict__ pooled) {
  const int idx = blockIdx.x * 256 + threadIdx.x;   // b*C + c
  const int b = idx / C_;
  const int c = idx - b * C_;
  float m = -INFINITY, s0 = 0.f, s1 = 0.f, s2 = 0.f;
#pragma unroll
  for (int p = 0; p < NT_; ++p) {
    const size_t j = ((size_t)(b * NT_ + p)) * C_ + c;
    float om = pm[j];
    if (om == -INFINITY) continue;
    float mn = fmaxf(m, om);
    float e1 = (m == -INFINITY) ? 0.f : __expf(m - mn);
    float e2 = __expf(om - mn);
    s0 = s0 * e1 + ps0[j] * e2;
    s1 = s1 * e1 + ps1[j] * e2;
    s2 = s2 * e1 + ps2[j] * e2;
    m = mn;
  }
  float mean = s1 / s0;
  float var = s2 / s0 - mean * mean;
  pooled[b * C2_ + c] = mean;
  pooled[b * C2_ + C_ + c] = sqrtf(fmaxf(var, 1e-5f));
}

// ---------------- K5: final LN over 2C channels per b -------------------------
__global__ __launch_bounds__(256) void k_final_ln(
    const float* __restrict__ pooled, const float* __restrict__ g2,
    const float* __restrict__ be2, float* __restrict__ out) {
  __shared__ float rs[8];
  const int b = blockIdx.x;
  const int tid = threadIdx.x;
  const int lane = tid & 63;
  const int wave = tid >> 6;
  const float* p = pooled + b * C2_;
  float s = 0.f, q = 0.f;
  for (int i = tid; i < C2_; i += 256) {
    float v = p[i];
    s += v;
    q += v * v;
  }
#pragma unroll
  for (int off = 32; off; off >>= 1) {
    s += __shfl_xor(s, off);
    q += __shfl_xor(q, off);
  }
  if (lane == 0) { rs[wave] = s; rs[4 + wave] = q; }
  __syncthreads();
  s = rs[0] + rs[1] + rs[2] + rs[3];
  q = rs[4] + rs[5] + rs[6] + rs[7];
  float mean = s * (1.f / C2_);
  float var = q * (1.f / C2_) - mean * mean;
  float rstd = rsqrtf(var + 1e-5f);
  for (int i = tid; i < C2_; i += 256)
    out[b * C2_ + i] = (p[i] - mean) * rstd * g2[i] + be2[i];
}

extern "C" void kernel_launch(void* const* d_in, const int* in_sizes, int n_in,
                              void* d_out, int out_size, void* d_ws, size_t ws_size,
                              hipStream_t stream) {
  const float* x    = (const float*)d_in[0];
  const float* mask = (const float*)d_in[1];
  const float* w1   = (const float*)d_in[2];
  const float* b1   = (const float*)d_in[3];
  const float* g1   = (const float*)d_in[4];
  const float* be1  = (const float*)d_in[5];
  const float* w2   = (const float*)d_in[6];
  // d_in[7] = b2: per-(b,c) constant on softmax logits -> softmax-invariant, dropped
  const float* g2   = (const float*)d_in[8];
  const float* be2  = (const float*)d_in[9];
  float* out = (float*)d_out;

  float* ws     = (float*)d_ws;
  float* mean0  = ws;                   // B*C
  float* std0   = mean0 + B_ * C_;      // B*C
  float* hconst = std0 + B_ * C_;       // B*H
  float* pooled = hconst + B_ * H_;     // B*2C
  float* pm     = pooled + B_ * C2_;    // B*NT*C each:
  float* ps0    = pm  + B_ * NT_ * C_;
  float* ps1    = ps0 + B_ * NT_ * C_;
  float* ps2    = ps1 + B_ * NT_ * C_;
  unsigned short* hlnT = (unsigned short*)(ps2 + B_ * NT_ * C_);  // B*T*H bf16, 8.2MB

  k_stats<<<dim3(B_ * C_ / 4), dim3(256), 0, stream>>>(x, mask, mean0, std0);
  k_hconst<<<dim3(B_ * H_ / 4), dim3(256), 0, stream>>>(w1, b1, mean0, std0, hconst);
  k_gemm1_ln<<<dim3((T_ + 63) / 64, B_), dim3(256), 0, stream>>>(x, w1, hconst, g1, be1, hlnT);
  k_gemm2_pool<<<dim3(C_ / 128, B_, NT_), dim3(256), 0, stream>>>(x, mask, w2, hlnT,
                                                                  pm, ps0, ps1, ps2);
  k_pool_merge<<<dim3(B_ * C_ / 256), dim3(256), 0, stream>>>(pm, ps0, ps1, ps2, pooled);
  k_final_ln<<<dim3(B_), dim3(256), 0, stream>>>(pooled, g2, be2, out);
}